// Round 1
// baseline (689.326 us; speedup 1.0000x reference)
//
#include <hip/hip_runtime.h>

// Otsu binarization: rgb(16,1024,1024,3) -> gray -> global otsu threshold -> {0,1}
// d_out doubles as the gray buffer between passes; ws holds minmax/hist/thresh.
//
// FP discipline: every op that feeds the threshold decision replicates the
// numpy float32 reference bit-for-bit (__f*_rn intrinsics, einsum L-to-R
// order, true division for bin index, sequential cumsums). A single flipped
// pixel fails the absmax check, so no FMA contraction / reciprocal tricks.

static constexpr float W0 = 0.2989f;
static constexpr float W1 = 0.5870f;
static constexpr float W2 = 0.1140f;

__device__ __forceinline__ float gray_of(float r, float g, float b) {
    // einsum 'bhwc,c->bhw': ((r*w0) + (g*w1)) + (b*w2), rn each step, no fma
    return __fadd_rn(__fadd_rn(__fmul_rn(r, W0), __fmul_rn(g, W1)), __fmul_rn(b, W2));
}

__global__ void k_init(unsigned* __restrict__ minmax, unsigned* __restrict__ hist) {
    int t = threadIdx.x;
    if (t == 0) { minmax[0] = 0x7f800000u; minmax[1] = 0u; }  // +inf, 0 (gray >= 0)
    if (t < 256) hist[t] = 0u;
}

__global__ void k_gray_minmax(const float4* __restrict__ in4, float4* __restrict__ gray4,
                              unsigned* __restrict__ minmax, int npix4) {
    int i = blockIdx.x * blockDim.x + threadIdx.x;
    float lmin = __uint_as_float(0x7f800000u);
    float lmax = 0.0f;
    if (i < npix4) {
        // 4 pixels = 12 floats = 3 float4 loads (contiguous 48B per thread)
        float4 a = in4[3 * i + 0];
        float4 b = in4[3 * i + 1];
        float4 c = in4[3 * i + 2];
        float g0 = gray_of(a.x, a.y, a.z);
        float g1 = gray_of(a.w, b.x, b.y);
        float g2 = gray_of(b.z, b.w, c.x);
        float g3 = gray_of(c.y, c.z, c.w);
        float4 o; o.x = g0; o.y = g1; o.z = g2; o.w = g3;
        gray4[i] = o;
        lmin = fminf(fminf(g0, g1), fminf(g2, g3));
        lmax = fmaxf(fmaxf(g0, g1), fmaxf(g2, g3));
    }
    // wave64 butterfly-ish reduce
    #pragma unroll
    for (int off = 32; off > 0; off >>= 1) {
        lmin = fminf(lmin, __shfl_down(lmin, off));
        lmax = fmaxf(lmax, __shfl_down(lmax, off));
    }
    __shared__ float smin[4], smax[4];
    int wave = threadIdx.x >> 6;
    int lane = threadIdx.x & 63;
    if (lane == 0) { smin[wave] = lmin; smax[wave] = lmax; }
    __syncthreads();
    if (threadIdx.x == 0) {
        float bmin = fminf(fminf(smin[0], smin[1]), fminf(smin[2], smin[3]));
        float bmax = fmaxf(fmaxf(smax[0], smax[1]), fmaxf(smax[2], smax[3]));
        // gray >= 0 so float ordering == uint ordering on the bit patterns
        atomicMin(&minmax[0], __float_as_uint(bmin));
        atomicMax(&minmax[1], __float_as_uint(bmax));
    }
}

__global__ void k_hist(const float4* __restrict__ gray4, const unsigned* __restrict__ minmax,
                       unsigned* __restrict__ hist, int npix4) {
    __shared__ unsigned lh[4 * 256];   // one 256-bin histogram per wave
    for (int j = threadIdx.x; j < 4 * 256; j += blockDim.x) lh[j] = 0u;
    __syncthreads();
    float mn = __uint_as_float(minmax[0]);
    float mx = __uint_as_float(minmax[1]);
    float width = __fdiv_rn(__fsub_rn(mx, mn), 256.0f);
    unsigned* myh = &lh[(threadIdx.x >> 6) * 256];
    int stride = gridDim.x * blockDim.x;
    for (int i = blockIdx.x * blockDim.x + threadIdx.x; i < npix4; i += stride) {
        float4 g = gray4[i];
        // reference: int32((x - mn) / width) clipped to [0,255] — true division
        int i0 = (int)__fdiv_rn(__fsub_rn(g.x, mn), width);
        int i1 = (int)__fdiv_rn(__fsub_rn(g.y, mn), width);
        int i2 = (int)__fdiv_rn(__fsub_rn(g.z, mn), width);
        int i3 = (int)__fdiv_rn(__fsub_rn(g.w, mn), width);
        i0 = min(max(i0, 0), 255);
        i1 = min(max(i1, 0), 255);
        i2 = min(max(i2, 0), 255);
        i3 = min(max(i3, 0), 255);
        atomicAdd(&myh[i0], 1u);
        atomicAdd(&myh[i1], 1u);
        atomicAdd(&myh[i2], 1u);
        atomicAdd(&myh[i3], 1u);
    }
    __syncthreads();
    for (int b = threadIdx.x; b < 256; b += blockDim.x) {
        unsigned total = lh[b] + lh[256 + b] + lh[512 + b] + lh[768 + b];
        if (total) atomicAdd(&hist[b], total);
    }
}

__global__ void k_otsu(const unsigned* __restrict__ minmax, const unsigned* __restrict__ hist,
                       float* __restrict__ thresh) {
    // Single thread: replicate numpy float32 sequential cumsums exactly.
    __shared__ float counts[256], centers[256], tt[256], w1[256], s1[256], w2[256], s2[256];
    if (threadIdx.x == 0) {
        float mn = __uint_as_float(minmax[0]);
        float mx = __uint_as_float(minmax[1]);
        float width = __fdiv_rn(__fsub_rn(mx, mn), 256.0f);
        for (int i = 0; i < 256; ++i) {
            counts[i] = (float)hist[i];                       // exact: counts <= 2^24
            centers[i] = __fadd_rn(mn, __fmul_rn(width, __fadd_rn((float)i, 0.5f)));
            tt[i] = __fmul_rn(counts[i], centers[i]);
        }
        float aw = 0.0f, as = 0.0f;
        for (int i = 0; i < 256; ++i) {                       // forward cumsum
            aw = __fadd_rn(aw, counts[i]); w1[i] = aw;
            as = __fadd_rn(as, tt[i]);     s1[i] = as;
        }
        aw = 0.0f; as = 0.0f;
        for (int i = 255; i >= 0; --i) {                      // reversed cumsum
            aw = __fadd_rn(aw, counts[i]); w2[i] = aw;
            as = __fadd_rn(as, tt[i]);     s2[i] = as;
        }
        float best = -1.0f; int bi = 0;
        for (int i = 0; i < 255; ++i) {
            float m1 = __fdiv_rn(s1[i],     fmaxf(w1[i],     1.0f));
            float m2 = __fdiv_rn(s2[i + 1], fmaxf(w2[i + 1], 1.0f));
            float d  = __fsub_rn(m1, m2);
            // python eval order: (w1*w2) * (d**2)
            float v  = __fmul_rn(__fmul_rn(w1[i], w2[i + 1]), __fmul_rn(d, d));
            if (v > best) { best = v; bi = i; }               // strict > == first argmax
        }
        *thresh = centers[bi];
    }
}

__global__ void k_bin(float4* __restrict__ g4, const float* __restrict__ thresh, int npix4) {
    int i = blockIdx.x * blockDim.x + threadIdx.x;
    float th = *thresh;
    if (i < npix4) {
        float4 g = g4[i];
        float4 o;
        o.x = g.x > th ? 1.0f : 0.0f;
        o.y = g.y > th ? 1.0f : 0.0f;
        o.z = g.z > th ? 1.0f : 0.0f;
        o.w = g.w > th ? 1.0f : 0.0f;
        g4[i] = o;
    }
}

extern "C" void kernel_launch(void* const* d_in, const int* in_sizes, int n_in,
                              void* d_out, int out_size, void* d_ws, size_t ws_size,
                              hipStream_t stream) {
    const float4* in4 = (const float4*)d_in[0];
    float4* gray4 = (float4*)d_out;          // d_out doubles as the gray buffer
    unsigned* wsu = (unsigned*)d_ws;
    unsigned* minmax = wsu;                  // [0]=min bits, [1]=max bits
    unsigned* hist = wsu + 2;                // 256 bins
    float* thresh = (float*)(wsu + 2 + 256); // 1 float

    int npix = in_sizes[0] / 3;              // 16*1024*1024
    int npix4 = npix / 4;
    int blocksA = (npix4 + 255) / 256;

    k_init<<<1, 256, 0, stream>>>(minmax, hist);
    k_gray_minmax<<<blocksA, 256, 0, stream>>>(in4, gray4, minmax, npix4);
    k_hist<<<1024, 256, 0, stream>>>((const float4*)d_out, minmax, hist, npix4);
    k_otsu<<<1, 64, 0, stream>>>(minmax, hist, thresh);
    k_bin<<<blocksA, 256, 0, stream>>>(gray4, thresh, npix4);
}

// Round 2
// 688.089 us; speedup vs baseline: 1.0018x; 1.0018x over previous
//
#include <hip/hip_runtime.h>

// Otsu binarization: rgb(16,1024,1024,3) -> gray -> global otsu threshold -> {0,1}
// d_out doubles as the gray buffer between passes; ws holds minmax/hist/thresh.
//
// FP discipline: every op that feeds the threshold decision replicates the
// numpy float32 reference bit-for-bit (__f*_rn intrinsics, einsum L-to-R
// order, true division for bin index, sequential cumsums). A single flipped
// pixel fails the absmax check, so no FMA contraction / reciprocal tricks.
//
// R1 lesson: 48B-lane-stride float4 loads ran at 442 GB/s (transaction
// amplification). Gray pass now stages the RGB tile through LDS with fully
// lane-contiguous global loads.

static constexpr float W0 = 0.2989f;
static constexpr float W1 = 0.5870f;
static constexpr float W2 = 0.1140f;

__device__ __forceinline__ float gray_of(float r, float g, float b) {
    // einsum 'bhwc,c->bhw': ((r*w0) + (g*w1)) + (b*w2), rn each step, no fma
    return __fadd_rn(__fadd_rn(__fmul_rn(r, W0), __fmul_rn(g, W1)), __fmul_rn(b, W2));
}

__global__ void k_init(unsigned* __restrict__ minmax, unsigned* __restrict__ hist) {
    int t = threadIdx.x;
    if (t == 0) { minmax[0] = 0x7f800000u; minmax[1] = 0u; }  // +inf, 0 (gray >= 0)
    if (t < 256) hist[t] = 0u;
}

// Each block: 1024 pixels = 3072 floats = 768 float4. Coalesced global->LDS,
// then per-thread 12-float reads from LDS, 4 grays out as one float4.
__global__ __launch_bounds__(256) void k_gray_minmax(
        const float4* __restrict__ in4, float4* __restrict__ gray4,
        unsigned* __restrict__ minmax) {
    __shared__ float s[3072];
    float4* sv = (float4*)s;
    const float4* src = in4 + (size_t)blockIdx.x * 768;
    int t = threadIdx.x;
    sv[t]       = src[t];          // lane-contiguous 16B: optimal global + LDS
    sv[t + 256] = src[t + 256];
    sv[t + 512] = src[t + 512];
    __syncthreads();

    float4 a = sv[3 * t + 0];      // s[12t .. 12t+3]
    float4 b = sv[3 * t + 1];
    float4 c = sv[3 * t + 2];
    float g0 = gray_of(a.x, a.y, a.z);
    float g1 = gray_of(a.w, b.x, b.y);
    float g2 = gray_of(b.z, b.w, c.x);
    float g3 = gray_of(c.y, c.z, c.w);
    float4 o; o.x = g0; o.y = g1; o.z = g2; o.w = g3;
    gray4[(size_t)blockIdx.x * 256 + t] = o;

    float lmin = fminf(fminf(g0, g1), fminf(g2, g3));
    float lmax = fmaxf(fmaxf(g0, g1), fmaxf(g2, g3));
    #pragma unroll
    for (int off = 32; off > 0; off >>= 1) {
        lmin = fminf(lmin, __shfl_down(lmin, off));
        lmax = fmaxf(lmax, __shfl_down(lmax, off));
    }
    __shared__ float smin[4], smax[4];
    int wave = t >> 6, lane = t & 63;
    if (lane == 0) { smin[wave] = lmin; smax[wave] = lmax; }
    __syncthreads();
    if (t == 0) {
        float bmin = fminf(fminf(smin[0], smin[1]), fminf(smin[2], smin[3]));
        float bmax = fmaxf(fmaxf(smax[0], smax[1]), fmaxf(smax[2], smax[3]));
        // gray >= 0 so float ordering == uint ordering on the bit patterns
        atomicMin(&minmax[0], __float_as_uint(bmin));
        atomicMax(&minmax[1], __float_as_uint(bmax));
    }
}

__global__ __launch_bounds__(256) void k_hist(
        const float4* __restrict__ gray4, const unsigned* __restrict__ minmax,
        unsigned* __restrict__ hist, int npix4) {
    __shared__ unsigned lh[4 * 256];   // one 256-bin histogram per wave
    for (int j = threadIdx.x; j < 4 * 256; j += blockDim.x) lh[j] = 0u;
    __syncthreads();
    float mn = __uint_as_float(minmax[0]);
    float mx = __uint_as_float(minmax[1]);
    float width = __fdiv_rn(__fsub_rn(mx, mn), 256.0f);
    unsigned* myh = &lh[(threadIdx.x >> 6) * 256];
    int stride = gridDim.x * blockDim.x;
    for (int i = blockIdx.x * blockDim.x + threadIdx.x; i < npix4; i += stride) {
        float4 g = gray4[i];
        // reference: int32((x - mn) / width) clipped to [0,255] — true division
        int i0 = (int)__fdiv_rn(__fsub_rn(g.x, mn), width);
        int i1 = (int)__fdiv_rn(__fsub_rn(g.y, mn), width);
        int i2 = (int)__fdiv_rn(__fsub_rn(g.z, mn), width);
        int i3 = (int)__fdiv_rn(__fsub_rn(g.w, mn), width);
        i0 = min(max(i0, 0), 255);
        i1 = min(max(i1, 0), 255);
        i2 = min(max(i2, 0), 255);
        i3 = min(max(i3, 0), 255);
        atomicAdd(&myh[i0], 1u);
        atomicAdd(&myh[i1], 1u);
        atomicAdd(&myh[i2], 1u);
        atomicAdd(&myh[i3], 1u);
    }
    __syncthreads();
    for (int b = threadIdx.x; b < 256; b += blockDim.x) {
        unsigned total = lh[b] + lh[256 + b] + lh[512 + b] + lh[768 + b];
        if (total) atomicAdd(&hist[b], total);
    }
}

__global__ void k_otsu(const unsigned* __restrict__ minmax, const unsigned* __restrict__ hist,
                       float* __restrict__ thresh) {
    // Single thread: replicate numpy float32 sequential cumsums exactly.
    __shared__ float counts[256], centers[256], tt[256], w1[256], s1[256], w2[256], s2[256];
    if (threadIdx.x == 0) {
        float mn = __uint_as_float(minmax[0]);
        float mx = __uint_as_float(minmax[1]);
        float width = __fdiv_rn(__fsub_rn(mx, mn), 256.0f);
        for (int i = 0; i < 256; ++i) {
            counts[i] = (float)hist[i];                       // exact: counts <= 2^24
            centers[i] = __fadd_rn(mn, __fmul_rn(width, __fadd_rn((float)i, 0.5f)));
            tt[i] = __fmul_rn(counts[i], centers[i]);
        }
        float aw = 0.0f, as = 0.0f;
        for (int i = 0; i < 256; ++i) {                       // forward cumsum
            aw = __fadd_rn(aw, counts[i]); w1[i] = aw;
            as = __fadd_rn(as, tt[i]);     s1[i] = as;
        }
        aw = 0.0f; as = 0.0f;
        for (int i = 255; i >= 0; --i) {                      // reversed cumsum
            aw = __fadd_rn(aw, counts[i]); w2[i] = aw;
            as = __fadd_rn(as, tt[i]);     s2[i] = as;
        }
        float best = -1.0f; int bi = 0;
        for (int i = 0; i < 255; ++i) {
            float m1 = __fdiv_rn(s1[i],     fmaxf(w1[i],     1.0f));
            float m2 = __fdiv_rn(s2[i + 1], fmaxf(w2[i + 1], 1.0f));
            float d  = __fsub_rn(m1, m2);
            // python eval order: (w1*w2) * (d**2)
            float v  = __fmul_rn(__fmul_rn(w1[i], w2[i + 1]), __fmul_rn(d, d));
            if (v > best) { best = v; bi = i; }               // strict > == first argmax
        }
        *thresh = centers[bi];
    }
}

__global__ __launch_bounds__(256) void k_bin(
        float4* __restrict__ g4, const float* __restrict__ thresh, int npix4) {
    int i = blockIdx.x * blockDim.x + threadIdx.x;
    float th = *thresh;
    if (i < npix4) {
        float4 g = g4[i];
        float4 o;
        o.x = g.x > th ? 1.0f : 0.0f;
        o.y = g.y > th ? 1.0f : 0.0f;
        o.z = g.z > th ? 1.0f : 0.0f;
        o.w = g.w > th ? 1.0f : 0.0f;
        g4[i] = o;
    }
}

extern "C" void kernel_launch(void* const* d_in, const int* in_sizes, int n_in,
                              void* d_out, int out_size, void* d_ws, size_t ws_size,
                              hipStream_t stream) {
    const float4* in4 = (const float4*)d_in[0];
    float4* gray4 = (float4*)d_out;          // d_out doubles as the gray buffer
    unsigned* wsu = (unsigned*)d_ws;
    unsigned* minmax = wsu;                  // [0]=min bits, [1]=max bits
    unsigned* hist = wsu + 2;                // 256 bins
    float* thresh = (float*)(wsu + 2 + 256); // 1 float

    int npix = in_sizes[0] / 3;              // 16*1024*1024
    int npix4 = npix / 4;
    int blocksGray = npix / 1024;            // 1024 pixels per block (exact)
    int blocksBin = (npix4 + 255) / 256;

    k_init<<<1, 256, 0, stream>>>(minmax, hist);
    k_gray_minmax<<<blocksGray, 256, 0, stream>>>(in4, gray4, minmax);
    k_hist<<<1024, 256, 0, stream>>>((const float4*)d_out, minmax, hist, npix4);
    k_otsu<<<1, 64, 0, stream>>>(minmax, hist, thresh);
    k_bin<<<blocksBin, 256, 0, stream>>>(gray4, thresh, npix4);
}

// Round 3
// 387.798 us; speedup vs baseline: 1.7775x; 1.7743x over previous
//
#include <hip/hip_runtime.h>

// Otsu binarization: rgb(16,1024,1024,3) -> gray -> global otsu threshold -> {0,1}
// d_out doubles as the gray buffer between passes; ws holds all partials.
//
// FP discipline: every op feeding the threshold decision replicates numpy
// float32 bit-for-bit (__f*_rn, einsum L-to-R order, true division, sequential
// cumsums on one thread). One flipped pixel fails absmax, so no FMA/rcp tricks.
//
// R2 lesson: load-pattern rewrite changed nothing -> bottleneck was the
// same-cacheline global atomics (32k serialized ops ~= 381 us). This version
// has ZERO global atomics: per-block partials + tiny reduce kernels.

static constexpr float W0 = 0.2989f;
static constexpr float W1 = 0.5870f;
static constexpr float W2 = 0.1140f;

__device__ __forceinline__ float gray_of(float r, float g, float b) {
    // einsum 'bhwc,c->bhw': ((r*w0) + (g*w1)) + (b*w2), rn each step, no fma
    return __fadd_rn(__fadd_rn(__fmul_rn(r, W0), __fmul_rn(g, W1)), __fmul_rn(b, W2));
}

// Grid-stride over 1024-pixel tiles. Per tile: coalesced global->LDS stage,
// per-thread 12-float LDS read, 4 grays out as one float4. Block min/max goes
// to partials (NO atomics).
__global__ __launch_bounds__(256) void k_gray(
        const float4* __restrict__ in4, float4* __restrict__ gray4,
        float* __restrict__ pmin, float* __restrict__ pmax, int ntiles) {
    __shared__ float4 sv[768];
    int t = threadIdx.x;
    float lmin = __uint_as_float(0x7f800000u);   // +inf
    float lmax = -lmin;                          // -inf
    for (int tile = blockIdx.x; tile < ntiles; tile += gridDim.x) {
        const float4* src = in4 + (size_t)tile * 768;
        float4 v0 = src[t];            // issue loads before the barrier so the
        float4 v1 = src[t + 256];      // VMEM latency overlaps the sync
        float4 v2 = src[t + 512];
        __syncthreads();               // previous iteration's LDS reads done
        sv[t] = v0; sv[t + 256] = v1; sv[t + 512] = v2;
        __syncthreads();
        float4 a = sv[3 * t + 0];
        float4 b = sv[3 * t + 1];
        float4 c = sv[3 * t + 2];
        float g0 = gray_of(a.x, a.y, a.z);
        float g1 = gray_of(a.w, b.x, b.y);
        float g2 = gray_of(b.z, b.w, c.x);
        float g3 = gray_of(c.y, c.z, c.w);
        float4 o; o.x = g0; o.y = g1; o.z = g2; o.w = g3;
        gray4[(size_t)tile * 256 + t] = o;
        lmin = fminf(lmin, fminf(fminf(g0, g1), fminf(g2, g3)));
        lmax = fmaxf(lmax, fmaxf(fmaxf(g0, g1), fmaxf(g2, g3)));
    }
    #pragma unroll
    for (int off = 32; off > 0; off >>= 1) {
        lmin = fminf(lmin, __shfl_down(lmin, off));
        lmax = fmaxf(lmax, __shfl_down(lmax, off));
    }
    __shared__ float smin[4], smax[4];
    int wave = t >> 6, lane = t & 63;
    if (lane == 0) { smin[wave] = lmin; smax[wave] = lmax; }
    __syncthreads();
    if (t == 0) {
        pmin[blockIdx.x] = fminf(fminf(smin[0], smin[1]), fminf(smin[2], smin[3]));
        pmax[blockIdx.x] = fmaxf(fmaxf(smax[0], smax[1]), fmaxf(smax[2], smax[3]));
    }
}

// Single block: reduce the per-block min/max partials.
__global__ __launch_bounds__(256) void k_reduce(
        const float* __restrict__ pmin, const float* __restrict__ pmax,
        float* __restrict__ minmax, int n) {
    int t = threadIdx.x;
    float lmin = __uint_as_float(0x7f800000u);
    float lmax = -lmin;
    for (int i = t; i < n; i += blockDim.x) {
        lmin = fminf(lmin, pmin[i]);
        lmax = fmaxf(lmax, pmax[i]);
    }
    #pragma unroll
    for (int off = 32; off > 0; off >>= 1) {
        lmin = fminf(lmin, __shfl_down(lmin, off));
        lmax = fmaxf(lmax, __shfl_down(lmax, off));
    }
    __shared__ float smin[4], smax[4];
    int wave = t >> 6, lane = t & 63;
    if (lane == 0) { smin[wave] = lmin; smax[wave] = lmax; }
    __syncthreads();
    if (t == 0) {
        minmax[0] = fminf(fminf(smin[0], smin[1]), fminf(smin[2], smin[3]));
        minmax[1] = fmaxf(fmaxf(smax[0], smax[1]), fmaxf(smax[2], smax[3]));
    }
}

// Per-wave LDS histograms; block writes its private 256-bin histogram to
// hist_part (coalesced stores, NO global atomics).
__global__ __launch_bounds__(256) void k_hist(
        const float4* __restrict__ gray4, const float* __restrict__ minmax,
        unsigned* __restrict__ hist_part, int npix4) {
    __shared__ unsigned lh[4 * 256];
    for (int j = threadIdx.x; j < 4 * 256; j += 256) lh[j] = 0u;
    __syncthreads();
    float mn = minmax[0];
    float mx = minmax[1];
    float width = __fdiv_rn(__fsub_rn(mx, mn), 256.0f);
    unsigned* myh = &lh[(threadIdx.x >> 6) << 8];
    int stride = gridDim.x * blockDim.x;
    for (int i = blockIdx.x * blockDim.x + threadIdx.x; i < npix4; i += stride) {
        float4 g = gray4[i];
        // reference: int32((x - mn) / width) clipped to [0,255] — true division
        int i0 = (int)__fdiv_rn(__fsub_rn(g.x, mn), width);
        int i1 = (int)__fdiv_rn(__fsub_rn(g.y, mn), width);
        int i2 = (int)__fdiv_rn(__fsub_rn(g.z, mn), width);
        int i3 = (int)__fdiv_rn(__fsub_rn(g.w, mn), width);
        i0 = min(max(i0, 0), 255);
        i1 = min(max(i1, 0), 255);
        i2 = min(max(i2, 0), 255);
        i3 = min(max(i3, 0), 255);
        atomicAdd(&myh[i0], 1u);   // LDS atomics only
        atomicAdd(&myh[i1], 1u);
        atomicAdd(&myh[i2], 1u);
        atomicAdd(&myh[i3], 1u);
    }
    __syncthreads();
    int b = threadIdx.x;   // exactly one bin per thread
    hist_part[(size_t)blockIdx.x * 256 + b] = lh[b] + lh[256 + b] + lh[512 + b] + lh[768 + b];
}

// One block, 1024 threads: sum partial hists in parallel, then the
// bit-exactness-mandated sequential pieces run on thread 0 out of LDS.
__global__ __launch_bounds__(1024) void k_otsu(
        const unsigned* __restrict__ hist_part, int nparts,
        const float* __restrict__ minmax, float* __restrict__ thresh) {
    __shared__ unsigned csum[4 * 256];
    __shared__ float counts[256], centers[256], tt[256];
    __shared__ float w1[256], s1[256], w2[256], s2[256], vv[256];
    int t = threadIdx.x;
    int b = t & 255, q = t >> 8;
    unsigned acc = 0;
    for (int k = q; k < nparts; k += 4)        // coalesced: thread b -> addr k*256+b
        acc += hist_part[(size_t)k * 256 + b];
    csum[q * 256 + b] = acc;
    __syncthreads();
    if (t < 256) {
        unsigned c = csum[t] + csum[256 + t] + csum[512 + t] + csum[768 + t];
        float mn = minmax[0];
        float mx = minmax[1];
        float width = __fdiv_rn(__fsub_rn(mx, mn), 256.0f);
        counts[t] = (float)c;                  // exact: counts <= 2^24
        centers[t] = __fadd_rn(mn, __fmul_rn(width, __fadd_rn((float)t, 0.5f)));
        tt[t] = __fmul_rn(counts[t], centers[t]);
    }
    __syncthreads();
    if (t == 0) {
        float aw = 0.0f, as = 0.0f;
        #pragma unroll 16
        for (int i = 0; i < 256; ++i) {        // forward cumsum (np order)
            aw = __fadd_rn(aw, counts[i]); w1[i] = aw;
            as = __fadd_rn(as, tt[i]);     s1[i] = as;
        }
        aw = 0.0f; as = 0.0f;
        #pragma unroll 16
        for (int i = 255; i >= 0; --i) {       // reversed cumsum
            aw = __fadd_rn(aw, counts[i]); w2[i] = aw;
            as = __fadd_rn(as, tt[i]);     s2[i] = as;
        }
    }
    __syncthreads();
    if (t < 255) {
        float m1 = __fdiv_rn(s1[t],     fmaxf(w1[t],     1.0f));
        float m2 = __fdiv_rn(s2[t + 1], fmaxf(w2[t + 1], 1.0f));
        float d  = __fsub_rn(m1, m2);
        // python eval order: (w1*w2) * (d**2)
        vv[t] = __fmul_rn(__fmul_rn(w1[t], w2[t + 1]), __fmul_rn(d, d));
    }
    __syncthreads();
    if (t == 0) {
        float best = -1.0f; int bi = 0;
        #pragma unroll 16
        for (int i = 0; i < 255; ++i) {        // strict > == first argmax
            float v = vv[i];
            if (v > best) { best = v; bi = i; }
        }
        *thresh = centers[bi];
    }
}

__global__ __launch_bounds__(256) void k_bin(
        float4* __restrict__ g4, const float* __restrict__ thresh, int npix4) {
    int i = blockIdx.x * blockDim.x + threadIdx.x;
    float th = *thresh;
    if (i < npix4) {
        float4 g = g4[i];
        float4 o;
        o.x = g.x > th ? 1.0f : 0.0f;
        o.y = g.y > th ? 1.0f : 0.0f;
        o.z = g.z > th ? 1.0f : 0.0f;
        o.w = g.w > th ? 1.0f : 0.0f;
        g4[i] = o;
    }
}

extern "C" void kernel_launch(void* const* d_in, const int* in_sizes, int n_in,
                              void* d_out, int out_size, void* d_ws, size_t ws_size,
                              hipStream_t stream) {
    const float4* in4 = (const float4*)d_in[0];
    float4* gray4 = (float4*)d_out;          // d_out doubles as the gray buffer

    int npix = in_sizes[0] / 3;              // 16*1024*1024
    int npix4 = npix / 4;
    int ntiles = npix / 1024;                // 16384
    int grayBlocks = ntiles < 2048 ? ntiles : 2048;

    // ws layout (all 4B-aligned)
    float* pmin = (float*)d_ws;                          // grayBlocks
    float* pmax = pmin + grayBlocks;                     // grayBlocks
    float* minmax = pmax + grayBlocks;                   // 2
    float* thresh = minmax + 2;                          // 1
    unsigned* hist_part = (unsigned*)(thresh + 1);       // histBlocks*256
    size_t used = (size_t)(2 * grayBlocks + 3) * sizeof(float);
    int histBlocks = 1024;
    if (ws_size < used + (size_t)histBlocks * 256 * sizeof(unsigned)) {
        size_t avail = (ws_size > used) ? (ws_size - used) : 0;
        histBlocks = (int)(avail / (256 * sizeof(unsigned)));
        if (histBlocks > 1024) histBlocks = 1024;
        if (histBlocks < 1) histBlocks = 1;
    }

    k_gray<<<grayBlocks, 256, 0, stream>>>(in4, gray4, pmin, pmax, ntiles);
    k_reduce<<<1, 256, 0, stream>>>(pmin, pmax, minmax, grayBlocks);
    k_hist<<<histBlocks, 256, 0, stream>>>((const float4*)d_out, minmax, hist_part, npix4);
    k_otsu<<<1, 1024, 0, stream>>>(hist_part, histBlocks, minmax, thresh);
    k_bin<<<(npix4 + 255) / 256, 256, 0, stream>>>(gray4, thresh, npix4);
}